// Round 8
// baseline (537.961 us; speedup 1.0000x reference)
//
#include <hip/hip_runtime.h>
#include <stdint.h>

#define N_NODES 100000
#define N_EDGES 1600000
#define D 128
#define NBUCK 196          // ceil(N_NODES/512); bucket b = dst >> 9
#define BSTRIDE 9216       // fixed pairs region per bucket (mean 8163, +11 sigma)
#define PCHUNK 2048        // edges per k_part block
#define NTILES (N_NODES / 16)   // 6250 exact
#define GRID_AG 2048

typedef unsigned int uint32;
typedef __attribute__((ext_vector_type(8))) short short8;   // 8 bf16 = 4 VGPRs
typedef __attribute__((ext_vector_type(4))) float f32x4;

__device__ __forceinline__ unsigned short f2bf(float f) {
  unsigned u = __builtin_bit_cast(unsigned, f);
  u += 0x7fffu + ((u >> 16) & 1u);          // round-to-nearest-even
  return (unsigned short)(u >> 16);
}
__device__ __forceinline__ float bflo(unsigned v) {
  return __builtin_bit_cast(float, v << 16);
}
__device__ __forceinline__ float bfhi(unsigned v) {
  return __builtin_bit_cast(float, v & 0xffff0000u);
}

// ---------------- CSR build (2 passes over edges, no global histogram) ------

__global__ __launch_bounds__(256) void k_part(const int* __restrict__ src,
                                              const int* __restrict__ dst,
                                              int* __restrict__ bcnt,
                                              uint2* __restrict__ pairs) {
  __shared__ uint2 buff[PCHUNK];     // 16 KB
  __shared__ uint2 sorted[PCHUNK];   // 16 KB
  __shared__ int hist[256], stmp[256], loff[256], cpos[256], base[256];
  int tid = threadIdx.x;
  int e0 = blockIdx.x * PCHUNK;
  int nv = N_EDGES - e0;
  if (nv > PCHUNK) nv = PCHUNK;

  hist[tid] = 0;
  __syncthreads();
  for (int i = tid; i < nv; i += 256) {
    int d = dst[e0 + i];
    int s = src[e0 + i];
    buff[i] = make_uint2((uint32)d, (uint32)s);
    atomicAdd(&hist[d >> 9], 1);
  }
  __syncthreads();
  int v = hist[tid];
  stmp[tid] = v;
  __syncthreads();
  for (int off = 1; off < 256; off <<= 1) {
    int t = (tid >= off) ? stmp[tid - off] : 0;
    __syncthreads();
    stmp[tid] += t;
    __syncthreads();
  }
  loff[tid] = stmp[tid] - v;
  cpos[tid] = stmp[tid] - v;
  base[tid] = (v > 0) ? atomicAdd(&bcnt[tid], v) : 0;
  __syncthreads();
  for (int i = tid; i < nv; i += 256) {
    uint2 p = buff[i];
    int r = atomicAdd(&cpos[p.x >> 9], 1);
    sorted[r] = p;
  }
  __syncthreads();
  for (int i = tid; i < nv; i += 256) {
    uint2 p = sorted[i];
    int b = (int)(p.x >> 9);
    int local = base[b] + (i - loff[b]);
    if (local < BSTRIDE)
      pairs[(size_t)b * BSTRIDE + local] = p;
  }
}

__global__ void k_scanb(const int* __restrict__ bcnt, int* __restrict__ bbase) {
  __shared__ int s[256];
  int tid = threadIdx.x;
  int v = (tid < NBUCK) ? bcnt[tid] : 0;
  s[tid] = v;
  __syncthreads();
  for (int off = 1; off < 256; off <<= 1) {
    int t = (tid >= off) ? s[tid - off] : 0;
    __syncthreads();
    s[tid] += t;
    __syncthreads();
  }
  if (tid <= NBUCK) bbase[tid] = s[tid] - v;
}

__global__ __launch_bounds__(512) void k_csr(const uint2* __restrict__ pairs,
                                             const int* __restrict__ bcnt,
                                             const int* __restrict__ bbase,
                                             int* __restrict__ rowptr,
                                             int* __restrict__ csr) {
  __shared__ int hist[512], off[512], cur[512];
  int b = blockIdx.x;
  int tid = threadIdx.x;
  int lo = b << 9;
  int hi = lo + 512;
  if (hi > N_NODES) hi = N_NODES;
  int ne = bcnt[b];
  if (ne > BSTRIDE) ne = BSTRIDE;
  const uint2* pb = pairs + (size_t)b * BSTRIDE;
  int bb = bbase[b];

  hist[tid] = 0;
  __syncthreads();
  for (int i = tid; i < ne; i += 512) atomicAdd(&hist[(int)pb[i].x - lo], 1);
  __syncthreads();
  int v = hist[tid];
  off[tid] = v;
  __syncthreads();
  for (int o = 1; o < 512; o <<= 1) {
    int t = (tid >= o) ? off[tid - o] : 0;
    __syncthreads();
    off[tid] += t;
    __syncthreads();
  }
  off[tid] -= v;
  cur[tid] = off[tid];
  if (lo + tid < hi) rowptr[lo + tid] = bb + off[tid];
  if (b == NBUCK - 1 && tid == 0) rowptr[N_NODES] = bbase[NBUCK];
  __syncthreads();
  for (int i = tid; i < ne; i += 512) {
    int d = (int)pb[i].x - lo;
    int slot = atomicAdd(&cur[d], 1);
    csr[bb + slot] = (int)pb[i].y;
  }
}

// ---------------- casts / weight packing ----------------

__global__ void k_cast(const float* __restrict__ in, unsigned short* __restrict__ ob, int n8) {
  int i = blockIdx.x * blockDim.x + threadIdx.x;
  if (i >= n8) return;
  float4 a = *reinterpret_cast<const float4*>(in + (size_t)i * 8);
  float4 b = *reinterpret_cast<const float4*>(in + (size_t)i * 8 + 4);
  uint4 o;
  o.x = (uint32)f2bf(a.x) | ((uint32)f2bf(a.y) << 16);
  o.y = (uint32)f2bf(a.z) | ((uint32)f2bf(a.w) << 16);
  o.z = (uint32)f2bf(b.x) | ((uint32)f2bf(b.y) << 16);
  o.w = (uint32)f2bf(b.z) | ((uint32)f2bf(b.w) << 16);
  *reinterpret_cast<uint4*>(ob + (size_t)i * 8) = o;
}

// Pack both layers' W = [Wl ; Wr] into mfma_f32_16x16x32_bf16 B-frag order.
__global__ void k_prepw2(const float* __restrict__ Wl1, const float* __restrict__ Wr1,
                         const float* __restrict__ Wl2, const float* __restrict__ Wr2,
                         unsigned short* __restrict__ Wp1,
                         unsigned short* __restrict__ Wp2) {
  int t = blockIdx.x * 256 + threadIdx.x;   // 65536
  int which = t >> 15;
  int tt = t & 32767;
  int j = tt & 7;
  int lane = (tt >> 3) & 63;
  int tile = (tt >> 9) & 1;
  int ks = (tt >> 10) & 7;
  int ng = (tt >> 13) & 3;
  int k = ks * 32 + (lane >> 4) * 8 + j;
  int n = ng * 32 + tile * 16 + (lane & 15);
  const float* Wl = which ? Wl2 : Wl1;
  const float* Wr = which ? Wr2 : Wr1;
  float w = (k < 128) ? Wl[k * 128 + n] : Wr[(k - 128) * 128 + n];
  (which ? Wp2 : Wp1)[tt] = f2bf(w);
}

// ---------------- fused mean-aggregate + MFMA GEMM ----------------
// Phase 1 is EDGE-PARALLEL: the tile's 16 nodes own one contiguous csr range;
// each 16-lane group takes an equal slice and flushes per-node partial sums
// into LDS via ds_add_f32 (segmented reduction) -> no degree divergence.
#define ACC8(v)                                          \
  acc[0] += bflo(v.x); acc[1] += bfhi(v.x);              \
  acc[2] += bflo(v.y); acc[3] += bfhi(v.y);              \
  acc[4] += bflo(v.z); acc[5] += bfhi(v.z);              \
  acc[6] += bflo(v.w); acc[7] += bfhi(v.w);

__global__ __launch_bounds__(256) void k_agg_gemm(
    const unsigned short* __restrict__ table,
    const int* __restrict__ rowptr, const int* __restrict__ csr,
    const unsigned short* __restrict__ Wp, const float* __restrict__ bias,
    void* __restrict__ outp, int relu_bf16_out) {
  __shared__ float meanS[16][132];   // +4 pad
  __shared__ int bnd[17];
  int tid = threadIdx.x;
  int wave = tid >> 6;
  int lane = tid & 63;
  int q = lane >> 4;
  int r = lane & 15;
  int g = tid >> 4;      // group 0..15
  int l = tid & 15;      // 16B column lane within group

  short8 Bf[8][2];
  const unsigned short* wp = Wp + ((size_t)wave * 8 * 2) * 64 * 8 + lane * 8;
#pragma unroll
  for (int ks = 0; ks < 8; ++ks)
#pragma unroll
    for (int t = 0; t < 2; ++t)
      Bf[ks][t] = *reinterpret_cast<const short8*>(wp + (ks * 2 + t) * 512);

  float bia0 = bias[wave * 32 + r];
  float bia1 = bias[wave * 32 + 16 + r];

  for (int tile = blockIdx.x; tile < NTILES; tile += GRID_AG) {
    int t16 = tile * 16;
    // x-half A-frags: independent -> issue before the gather
    const unsigned short* ax = table + (size_t)(t16 + r) * D + q * 8;
    short8 A[8];
#pragma unroll
    for (int ks = 0; ks < 4; ++ks)
      A[4 + ks] = *reinterpret_cast<const short8*>(ax + ks * 32);

    if (tid < 17) bnd[tid] = rowptr[t16 + tid];
    {  // zero exactly the 8 floats this thread's flushes/GEMM will touch
      float4 z = make_float4(0.f, 0.f, 0.f, 0.f);
      *reinterpret_cast<float4*>(&meanS[g][l * 8]) = z;
      *reinterpret_cast<float4*>(&meanS[g][l * 8 + 4]) = z;
    }
    __syncthreads();

    // ---- phase 1: balanced edge-parallel segmented sum ----
    int eb = bnd[0], ee = bnd[16];
    int nE = ee - eb;
    int per = (nE + 15) >> 4;
    int s = eb + g * per;
    int sEnd = s + per;
    if (sEnd > ee) sEnd = ee;
    if (s < sEnd) {
      int cn = 0;
      while (s >= bnd[cn + 1]) ++cn;    // first node of this slice
      float acc[8] = {0.f, 0.f, 0.f, 0.f, 0.f, 0.f, 0.f, 0.f};
      int e = s;
      while (e < sEnd) {
        int nodeEnd = bnd[cn + 1];
        int lim = nodeEnd < sEnd ? nodeEnd : sEnd;
        int segStart = e;
        for (; e + 3 < lim; e += 4) {   // 4 gathers in flight
          int s0 = csr[e], s1 = csr[e + 1], s2 = csr[e + 2], s3 = csr[e + 3];
          uint4 v0 = *reinterpret_cast<const uint4*>(table + (size_t)s0 * D + l * 8);
          uint4 v1 = *reinterpret_cast<const uint4*>(table + (size_t)s1 * D + l * 8);
          uint4 v2 = *reinterpret_cast<const uint4*>(table + (size_t)s2 * D + l * 8);
          uint4 v3 = *reinterpret_cast<const uint4*>(table + (size_t)s3 * D + l * 8);
          ACC8(v0) ACC8(v1) ACC8(v2) ACC8(v3)
        }
        for (; e < lim; ++e) {
          int s0 = csr[e];
          uint4 v0 = *reinterpret_cast<const uint4*>(table + (size_t)s0 * D + l * 8);
          ACC8(v0)
        }
        if (e > segStart) {             // flush partial sum for node cn
#pragma unroll
          for (int j = 0; j < 8; ++j) atomicAdd(&meanS[cn][l * 8 + j], acc[j]);
#pragma unroll
          for (int j = 0; j < 8; ++j) acc[j] = 0.f;
        }
        if (lim == nodeEnd) ++cn;
      }
    }
    __syncthreads();

    // ---- phase 2: [mean | x] @ Wp (1/deg folded into A build) ----
    int deg = bnd[r + 1] - bnd[r];
    float inv = (deg > 0) ? 1.0f / (float)deg : 0.0f;
#pragma unroll
    for (int ks = 0; ks < 4; ++ks) {
      float4 a0 = *reinterpret_cast<const float4*>(&meanS[r][ks * 32 + q * 8]);
      float4 a1 = *reinterpret_cast<const float4*>(&meanS[r][ks * 32 + q * 8 + 4]);
      short8 a;
      a[0] = (short)f2bf(a0.x * inv); a[1] = (short)f2bf(a0.y * inv);
      a[2] = (short)f2bf(a0.z * inv); a[3] = (short)f2bf(a0.w * inv);
      a[4] = (short)f2bf(a1.x * inv); a[5] = (short)f2bf(a1.y * inv);
      a[6] = (short)f2bf(a1.z * inv); a[7] = (short)f2bf(a1.w * inv);
      A[ks] = a;
    }

    f32x4 c0 = {0.f, 0.f, 0.f, 0.f}, c1 = {0.f, 0.f, 0.f, 0.f};
#pragma unroll
    for (int ks = 0; ks < 8; ++ks) {
      c0 = __builtin_amdgcn_mfma_f32_16x16x32_bf16(A[ks], Bf[ks][0], c0, 0, 0, 0);
      c1 = __builtin_amdgcn_mfma_f32_16x16x32_bf16(A[ks], Bf[ks][1], c1, 0, 0, 0);
    }

    int orow = t16 + q * 4;   // C: col=lane&15, row=quad*4+reg
    if (relu_bf16_out) {
      unsigned short* ob = (unsigned short*)outp + (size_t)orow * D + wave * 32 + r;
#pragma unroll
      for (int gg = 0; gg < 4; ++gg) {
        ob[(size_t)gg * D] = f2bf(fmaxf(c0[gg] + bia0, 0.f));
        ob[(size_t)gg * D + 16] = f2bf(fmaxf(c1[gg] + bia1, 0.f));
      }
    } else {
      float* of = (float*)outp + (size_t)orow * D + wave * 32 + r;
#pragma unroll
      for (int gg = 0; gg < 4; ++gg) {
        of[(size_t)gg * D] = c0[gg] + bia0;
        of[(size_t)gg * D + 16] = c1[gg] + bia1;
      }
    }
    __syncthreads();   // meanS/bnd reused next tile
  }
}

// ---------------- launch ----------------

extern "C" void kernel_launch(void* const* d_in, const int* in_sizes, int n_in,
                              void* d_out, int out_size, void* d_ws, size_t ws_size,
                              hipStream_t stream) {
  const float* x   = (const float*)d_in[0];
  const int*   ei  = (const int*)d_in[1];
  const float* Wl1 = (const float*)d_in[2];
  const float* Wr1 = (const float*)d_in[3];
  const float* b1  = (const float*)d_in[4];
  const float* Wl2 = (const float*)d_in[5];
  const float* Wr2 = (const float*)d_in[6];
  const float* b2  = (const float*)d_in[7];
  float* out = (float*)d_out;

  const int* esrc = ei;
  const int* edst = ei + N_EDGES;

  char* p = (char*)d_ws;
  auto take = [&](size_t bytes) {
    char* q = p;
    p += (bytes + 255) & ~(size_t)255;
    return q;
  };
  int* bcnt   = (int*)take(256 * 4);
  int* bbase  = (int*)take(257 * 4);
  int* rowptr = (int*)take((size_t)(N_NODES + 1) * 4);
  int* csr    = (int*)take((size_t)N_EDGES * 4);
  uint2* pairs = (uint2*)take((size_t)NBUCK * BSTRIDE * 8);   // 14.5 MB
  unsigned short* xb  = (unsigned short*)take((size_t)N_NODES * D * 2);
  unsigned short* hb  = (unsigned short*)take((size_t)N_NODES * D * 2);
  unsigned short* Wp1 = (unsigned short*)take(256 * 128 * 2);
  unsigned short* Wp2 = (unsigned short*)take(256 * 128 * 2);

  const int npart = (N_EDGES + PCHUNK - 1) / PCHUNK;   // 782

  hipMemsetAsync(bcnt, 0, 256 * 4, stream);
  k_part<<<npart, 256, 0, stream>>>(esrc, edst, bcnt, pairs);
  k_scanb<<<1, 256, 0, stream>>>(bcnt, bbase);
  k_csr<<<NBUCK, 512, 0, stream>>>(pairs, bcnt, bbase, rowptr, csr);

  k_cast<<<(N_NODES * D / 8 + 255) / 256, 256, 0, stream>>>(x, xb, N_NODES * D / 8);
  k_prepw2<<<256, 256, 0, stream>>>(Wl1, Wr1, Wl2, Wr2, Wp1, Wp2);

  // layer 1: hb = relu([mean(xb)|xb] @ Wp1 + b1)   (bf16 out)
  k_agg_gemm<<<GRID_AG, 256, 0, stream>>>(xb, rowptr, csr, Wp1, b1, hb, 1);
  // layer 2: out = [mean(hb)|hb] @ Wp2 + b2        (f32 out)
  k_agg_gemm<<<GRID_AG, 256, 0, stream>>>(hb, rowptr, csr, Wp2, b2, out, 0);
}